// Round 3
// baseline (426.864 us; speedup 1.0000x reference)
//
#include <hip/hip_runtime.h>

#define DET 1024
#define T_TOTAL 3072
#define CLIPV 20.0f

// DPP lane permutation (ctrl: quad_perm imm8, 0x140 row_mirror, 0x141 row_half_mirror).
// Pure VALU, standard GCN3+ semantics.
template<int CTRL>
__device__ __forceinline__ float dppx(float v) {
    int i = __float_as_int(v);
    int r = __builtin_amdgcn_update_dpp(i, i, CTRL, 0xF, 0xF, false);
    return __int_as_float(r);
}

// One block = one wave = one batch element.
// Butterfly relabeling: lane L holds M_t[rotr6(L, t%6)].
// Step t (k=t%6): partner lane = L ^ (1<<k); lane L produces state
// sn = rotr6(L, (k+1)%6); input bit b = sn>>5 = bit k of L; own-held value
// is M_t[prev_b], partner holds M_t[prev_(1-b)], prev_j = (2*sn+j)&63.
__global__ __launch_bounds__(64) void cva_kernel(const float* __restrict__ x,
                                                 float* __restrict__ out) {
    const int bidx = blockIdx.x;
    const int L = threadIdx.x;

    __shared__ float2 lx[DET];               // staged LLR pairs, 8 KB
    __shared__ unsigned int dec2[96 * 64];   // [t/32][lane] decision bits, 24 KB
    __shared__ unsigned int bitw[DET / 32];  // output bits

    const float2* __restrict__ xrow =
        reinterpret_cast<const float2*>(x + (size_t)bidx * (2 * DET));
    for (int i = L; i < DET; i += 64) lx[i] = xrow[i];
    __syncthreads();

    // per-phase, per-lane constants (k-loop fully unrolled -> registers)
    bool eo0[6], eo1[6], ep0[6], ep1[6], bb[6];
    #pragma unroll
    for (int k = 0; k < 6; ++k) {
        int r = (k + 1) % 6;
        int sn = ((L >> r) | (L << (6 - r))) & 63;   // rotr6(L, r)
        int b = (sn >> 5) & 1;
        int q0 = (sn << 1) & 63;                     // prev_0
        int q1 = q0 | 1;                             // prev_1
        int qo = b ? q1 : q0;                        // own candidate (j = b)
        int qp = b ? q0 : q1;                        // partner candidate (j = 1-b)
        // GM row0: c0 = b^p5^p4^p3^p0 ; row1: c1 = b^p4^p3^p1^p0
        eo0[k] = ((b ^ (qo >> 5) ^ (qo >> 4) ^ (qo >> 3) ^ qo) & 1) != 0;
        eo1[k] = ((b ^ (qo >> 4) ^ (qo >> 3) ^ (qo >> 1) ^ qo) & 1) != 0;
        ep0[k] = ((b ^ (qp >> 5) ^ (qp >> 4) ^ (qp >> 3) ^ qp) & 1) != 0;
        ep1[k] = ((b ^ (qp >> 4) ^ (qp >> 3) ^ (qp >> 1) ^ qp) & 1) != 0;
        bb[k] = (b != 0);
    }

    // ---- forward ACS: 512 x 6 phases ----
    float m = 0.0f;
    unsigned int acc = 0;
    for (int t6 = 0; t6 < 512; ++t6) {
        #pragma unroll
        for (int k = 0; k < 6; ++k) {
            const int t = t6 * 6 + k;
            float2 ll = lx[t & (DET - 1)];            // wave-uniform broadcast
            float Bo = (eo0[k] ? ll.x : 0.0f) + (eo1[k] ? ll.y : 0.0f);
            float Bp = (ep0[k] ? ll.x : 0.0f) + (ep1[k] ? ll.y : 0.0f);
            float mp;
            if (k == 0)      mp = dppx<0xB1>(m);                 // xor1: [1,0,3,2]
            else if (k == 1) mp = dppx<0x4E>(m);                 // xor2: [2,3,0,1]
            else if (k == 2) mp = dppx<0x141>(dppx<0x1B>(m));    // xor7∘xor3 = xor4
            else if (k == 3) mp = dppx<0x140>(dppx<0x141>(m));   // xor15∘xor7 = xor8
            else if (k == 4) mp = __shfl(m, L ^ 16, 64);         // xor16 (bpermute)
            else             mp = __shfl(m, L ^ 32, 64);         // xor32 (bpermute)
            float to = m + Bo;                        // candidate j = b
            float tp = mp + Bp;                       // candidate j = 1-b
            bool d = bb[k] ? (to < tp) : (tp < to);   // argmin, tie -> j=0
            float mn = fminf(to, tp);
            m = fminf(fmaxf(mn, -CLIPV), CLIPV);
            acc |= d ? (1u << (t & 31)) : 0u;
            if (((t + 1) & 31) == 0) {                // wave-uniform
                dec2[(t >> 5) * 64 + L] = acc;
                acc = 0;
            }
        }
    }
    __syncthreads();

    // ---- serial traceback (lane 0) ----
    // decision for state s at time t is at lane Lx = rotl6(s, (t+1)%6),
    // word dec2[t>>5][Lx], bit (t&31).
    if (L == 0) {
        int st = 0;
        for (int t = T_TOTAL - 1; t >= 2 * DET; --t) {    // discard top replication
            int r = (t + 1) % 6;
            int Lx = ((st << r) | (st >> (6 - r))) & 63;  // rotl6(st, r)
            int d = (int)((dec2[(t >> 5) * 64 + Lx] >> (t & 31)) & 1u);
            st = ((st << 1) | d) & 63;
        }
        unsigned int ac2 = 0;
        for (int i = DET - 1; i >= 0; --i) {              // middle replication
            int t = DET + i;
            unsigned int bit = (~(unsigned)st) & 1u;      // (state+1)%2
            ac2 |= bit << (i & 31);
            if ((i & 31) == 0) { bitw[i >> 5] = ac2; ac2 = 0; }
            int r = (t + 1) % 6;
            int Lx = ((st << r) | (st >> (6 - r))) & 63;
            int d = (int)((dec2[(t >> 5) * 64 + Lx] >> (t & 31)) & 1u);
            st = ((st << 1) | d) & 63;
        }
    }
    __syncthreads();

    // ---- coalesced output ----
    float* orow = out + (size_t)bidx * DET;
    #pragma unroll
    for (int c = 0; c < 16; ++c) {
        int i = c * 64 + L;
        orow[i] = (float)((bitw[i >> 5] >> (i & 31)) & 1u);
    }
}

extern "C" void kernel_launch(void* const* d_in, const int* in_sizes, int n_in,
                              void* d_out, int out_size, void* d_ws, size_t ws_size,
                              hipStream_t stream) {
    const float* x = (const float*)d_in[0];
    float* out = (float*)d_out;
    (void)in_sizes; (void)n_in; (void)d_ws; (void)ws_size; (void)out_size;
    hipLaunchKernelGGL(cva_kernel, dim3(512), dim3(64), 0, stream, x, out);
}

// Round 4
// 305.480 us; speedup vs baseline: 1.3974x; 1.3974x over previous
//
#include <hip/hip_runtime.h>

#define DET 1024
#define T_TOTAL 3072
#define CLIPV 20.0f
#define NW 4            // waves per block
#define CHUNK 512       // traceback chunk length (NW*CHUNK = 2048)

// DPP lane permutation (ctrl: quad_perm imm8, 0x140 row_mirror, 0x141 row_half_mirror)
template<int CTRL>
__device__ __forceinline__ float dppx(float v) {
    int i = __float_as_int(v);
    int r = __builtin_amdgcn_update_dpp(i, i, CTRL, 0xF, 0xF, false);
    return __int_as_float(r);
}

// One block = one batch element. Wave 0: forward ACS (lane = butterfly-labeled
// state, lane L holds M_t[rotr6(L, t%6)]). All 4 waves: speculative traceback.
__global__ __launch_bounds__(64 * NW) void cva_kernel(const float* __restrict__ x,
                                                      float* __restrict__ out) {
    const int bidx = blockIdx.x;
    const int tid  = threadIdx.x;
    const int L    = tid & 63;
    const int w    = tid >> 6;

    __shared__ float2 lx[DET];                    // 8 KB staged LLR pairs
    __shared__ unsigned int dec2[96 * 64];        // 24 KB decision bits [t/32][lane]
    __shared__ unsigned int bitsl[2][64][16];     // 8 KB spec. bit strings (chunks 0,1)
    __shared__ unsigned char gmap[NW][64];        // chunk state maps
    __shared__ unsigned char entry[NW];           // true entry state per chunk
    __shared__ unsigned int bitw[DET / 32];       // final output bits

    // ---- stage LLRs (all threads, coalesced) ----
    const float2* __restrict__ xrow =
        reinterpret_cast<const float2*>(x + (size_t)bidx * (2 * DET));
    for (int i = tid; i < DET; i += 64 * NW) lx[i] = xrow[i];
    __syncthreads();

    // ---- forward ACS: wave 0 only ----
    if (w == 0) {
        // per-phase, per-lane constants (fully unrolled -> registers)
        bool eo0[6], eo1[6], ep0[6], ep1[6], bb[6];
        #pragma unroll
        for (int k = 0; k < 6; ++k) {
            int r = (k + 1) % 6;
            int sn = ((L >> r) | (L << (6 - r))) & 63;   // rotr6(L, r)
            int b = (sn >> 5) & 1;
            int q0 = (sn << 1) & 63;
            int q1 = q0 | 1;
            int qo = b ? q1 : q0;                        // own candidate (j = b)
            int qp = b ? q0 : q1;                        // partner candidate (j = 1-b)
            eo0[k] = ((b ^ (qo >> 5) ^ (qo >> 4) ^ (qo >> 3) ^ qo) & 1) != 0;
            eo1[k] = ((b ^ (qo >> 4) ^ (qo >> 3) ^ (qo >> 1) ^ qo) & 1) != 0;
            ep0[k] = ((b ^ (qp >> 5) ^ (qp >> 4) ^ (qp >> 3) ^ qp) & 1) != 0;
            ep1[k] = ((b ^ (qp >> 4) ^ (qp >> 3) ^ (qp >> 1) ^ qp) & 1) != 0;
            bb[k] = (b != 0);
        }

        float m = 0.0f;
        unsigned int acc = 0;
        float2 nll[6];
        #pragma unroll
        for (int j = 0; j < 6; ++j) nll[j] = lx[j];      // prefetch group 0
        for (int t6 = 0; t6 < 512; ++t6) {
            float2 cll[6];
            #pragma unroll
            for (int j = 0; j < 6; ++j) cll[j] = nll[j];
            const int nb = (t6 + 1) * 6;                 // prefetch next group
            #pragma unroll
            for (int j = 0; j < 6; ++j) nll[j] = lx[(nb + j) & (DET - 1)];
            #pragma unroll
            for (int k = 0; k < 6; ++k) {
                const int t = t6 * 6 + k;
                float2 ll = cll[k];                      // in-register, no LDS wait
                float Bo = (eo0[k] ? ll.x : 0.0f) + (eo1[k] ? ll.y : 0.0f);
                float Bp = (ep0[k] ? ll.x : 0.0f) + (ep1[k] ? ll.y : 0.0f);
                float mp;
                if (k == 0)      mp = dppx<0xB1>(m);                 // xor1
                else if (k == 1) mp = dppx<0x4E>(m);                 // xor2
                else if (k == 2) mp = dppx<0x141>(dppx<0x1B>(m));    // xor4
                else if (k == 3) mp = dppx<0x140>(dppx<0x141>(m));   // xor8
                else if (k == 4) mp = __shfl(m, L ^ 16, 64);         // xor16
                else             mp = __shfl(m, L ^ 32, 64);         // xor32
                float to = m + Bo;                       // candidate j = b
                float tp = mp + Bp;                      // candidate j = 1-b
                bool d = bb[k] ? (to < tp) : (tp < to);  // argmin, tie -> j=0
                float mn = fminf(to, tp);
                m = fminf(fmaxf(mn, -CLIPV), CLIPV);
                acc |= d ? (1u << (t & 31)) : 0u;
                if (((t + 1) & 31) == 0) {               // wave-uniform
                    dec2[(t >> 5) * 64 + L] = acc;
                    acc = 0;
                }
            }
        }
    }
    __syncthreads();

    // ---- speculative traceback: wave w handles t in [1024+512w, 1024+512(w+1)),
    //      lane L = assumed state at chunk's high boundary ----
    {
        int st = L;
        unsigned int ac2 = 0;
        const int tlo = 1024 + CHUNK * w;
        #pragma unroll 4
        for (int t = tlo + CHUNK - 1; t >= tlo; --t) {
            if (t < 2048) {                              // middle replication: emit
                unsigned int bit = (~(unsigned)st) & 1u; // (state+1)%2, pre-update
                ac2 |= bit << (t & 31);
                if ((t & 31) == 0) { bitsl[w][L][(t >> 5) & 15] = ac2; ac2 = 0; }
            }
            int r = (t + 1) % 6;
            int Lx = ((st << r) | (st >> (6 - r))) & 63; // rotl6(st, r)
            int d = (int)((dec2[(t >> 5) * 64 + Lx] >> (t & 31)) & 1u);
            st = ((st << 1) | d) & 63;
        }
        gmap[w][L] = (unsigned char)st;
    }
    __syncthreads();

    // ---- compose chunk maps: true start state at t=3071 boundary is 0 ----
    if (tid == 0) {
        int s = 0;
        for (int wc = NW - 1; wc >= 0; --wc) {
            entry[wc] = (unsigned char)s;
            s = gmap[wc][s];
        }
    }
    __syncthreads();

    // ---- gather the true path's bits (chunks 0,1 carry output bits) ----
    if (tid < 32) {
        int wc = tid >> 4;
        bitw[tid] = bitsl[wc][entry[wc]][tid & 15];
    }
    __syncthreads();

    // ---- coalesced output store ----
    float* orow = out + (size_t)bidx * DET;
    #pragma unroll
    for (int c = 0; c < 4; ++c) {
        int i = c * (64 * NW) + tid;
        orow[i] = (float)((bitw[i >> 5] >> (i & 31)) & 1u);
    }
}

extern "C" void kernel_launch(void* const* d_in, const int* in_sizes, int n_in,
                              void* d_out, int out_size, void* d_ws, size_t ws_size,
                              hipStream_t stream) {
    const float* x = (const float*)d_in[0];
    float* out = (float*)d_out;
    (void)in_sizes; (void)n_in; (void)d_ws; (void)ws_size; (void)out_size;
    hipLaunchKernelGGL(cva_kernel, dim3(512), dim3(64 * NW), 0, stream, x, out);
}

// Round 5
// 297.487 us; speedup vs baseline: 1.4349x; 1.0269x over previous
//
#include <hip/hip_runtime.h>

#define DET 1024
#define CLIPV 20.0f

// DPP lane permutation (quad_perm imm8, 0x140 row_mirror, 0x141 row_half_mirror)
template<int CTRL>
__device__ __forceinline__ float dppx(float v) {
    int i = __float_as_int(v);
    int r = __builtin_amdgcn_update_dpp(i, i, CTRL, 0xF, 0xF, false);
    return __int_as_float(r);
}

// Full exchange lane^16 via gfx950 v_permlane16_swap_b32.
// After swapping two distinct copies of v, each lane's {a,b} = {own, partner}
// as a set (either swap-direction convention). Bitwise equality-select picks
// the partner; ties are value-equal so either pick is identical.
__device__ __forceinline__ float xor16x(float v) {
    int a = __float_as_int(v);
    int b;
    asm("v_mov_b32 %1, %0\n\t"
        "s_nop 1\n\t"
        "v_permlane16_swap_b32 %0, %1\n\t"
        "s_nop 1"
        : "+v"(a), "=&v"(b));
    int mi = __float_as_int(v);
    return __int_as_float((a == mi) ? b : a);
}
// Full exchange lane^32 via v_permlane32_swap_b32 (same construction).
__device__ __forceinline__ float xor32x(float v) {
    int a = __float_as_int(v);
    int b;
    asm("v_mov_b32 %1, %0\n\t"
        "s_nop 1\n\t"
        "v_permlane32_swap_b32 %0, %1\n\t"
        "s_nop 1"
        : "+v"(a), "=&v"(b));
    int mi = __float_as_int(v);
    return __int_as_float((a == mi) ? b : a);
}

// One ACS step. Butterfly labeling: lane L holds M_t[rotr6(L, t%6)];
// phase k = t%6, partner = L ^ (1<<k), input bit b = bit k of L.
#define STEP(LL, K, T) do {                                                    \
    const float _llx = (LL).x, _lly = (LL).y;                                  \
    float Bo = (eo0[K] ? _llx : 0.0f) + (eo1[K] ? _lly : 0.0f);                \
    float Bp = (ep0[K] ? _llx : 0.0f) + (ep1[K] ? _lly : 0.0f);                \
    float mp;                                                                  \
    if ((K) == 0)      mp = dppx<0xB1>(m);                /* xor1 */           \
    else if ((K) == 1) mp = dppx<0x4E>(m);                /* xor2 */           \
    else if ((K) == 2) mp = dppx<0x141>(dppx<0x1B>(m));   /* xor4 */           \
    else if ((K) == 3) mp = dppx<0x140>(dppx<0x141>(m));  /* xor8 */           \
    else if ((K) == 4) mp = xor16x(m);                    /* xor16 */          \
    else               mp = xor32x(m);                    /* xor32 */          \
    float to = m + Bo;                                    /* candidate j=b  */ \
    float tp = mp + Bp;                                   /* candidate j=1-b*/ \
    unsigned long long lt_o = __ballot(to < tp);                               \
    unsigned long long lt_p = __ballot(tp < to);                               \
    unsigned long long bal = (BBM[K] & lt_o) | (~BBM[K] & lt_p);               \
    float mn = fminf(to, tp);                                                  \
    m = __builtin_amdgcn_fmed3f(mn, -CLIPV, CLIPV);                            \
    if ((T) >= DET && L == 0) dq[(T) - DET] = bal;                             \
} while (0)

// 8 traceback steps from qword buffer QARR; t = TBTOP - j; RT = (TBTOP+1)%6.
#define TBSTEPS(QARR, TBTOP, RT) do {                                          \
    _Pragma("unroll")                                                          \
    for (int j = 0; j < 8; ++j) {                                              \
        const int t = (TBTOP) - j;                                             \
        int r = (RT) - (j % 6); if (r < 0) r += 6;                             \
        int Lx = ((st << r) | (st >> (6 - r))) & 63;                           \
        int bit = (int)((QARR[j] >> Lx) & 1ull);                               \
        if (c < 2) {                                                           \
            unsigned int ob = (~(unsigned)st) & 1u;                            \
            int i = t - 1024;                                                  \
            acc |= ob << (i & 31);                                             \
            if ((i & 31) == 0) { bitsl[q][c][L][(i >> 5) & 15] = acc; acc = 0; }\
        }                                                                      \
        st = ((st << 1) | bit) & 63;                                           \
    }                                                                          \
} while (0)

// 256 blocks x 512 threads; each block owns batches 2*bidx, 2*bidx+1.
// Waves 0,1: forward ACS (different SIMDs). All 8 waves: traceback.
__global__ __launch_bounds__(512) void cva_kernel(const float* __restrict__ x,
                                                  float* __restrict__ out) {
    const int bidx = blockIdx.x;
    const int tid  = threadIdx.x;
    const int L    = tid & 63;
    const int w    = tid >> 6;

    __shared__ float2 lx[2][DET];                 // 16 KB
    __shared__ unsigned long long decs[2][2048];  // 32 KB, indexed by t-1024
    __shared__ unsigned int bitsl[2][2][64][16];  // 16 KB (emit chunks 0,1)
    __shared__ unsigned char gmap[2][4][64];
    __shared__ unsigned char entry[2][4];
    __shared__ unsigned int bitw[2][32];

    // ---- stage both batches' LLRs (coalesced) ----
    const float2* __restrict__ xr2 =
        reinterpret_cast<const float2*>(x + (size_t)bidx * 4096);
    float2* lxf = &lx[0][0];
    for (int i = tid; i < 2048; i += 512) lxf[i] = xr2[i];
    __syncthreads();

    // ---- forward ACS: waves 0,1 (one batch each) ----
    if (w < 2) {
        const float2* lq = &lx[w][0];
        unsigned long long* dq = &decs[w][0];

        // per-phase per-lane edge constants (verified in rounds 3/4)
        bool eo0[6], eo1[6], ep0[6], ep1[6];
        #pragma unroll
        for (int k = 0; k < 6; ++k) {
            int r = (k + 1) % 6;
            int sn = ((L >> r) | (L << (6 - r))) & 63;   // rotr6(L, r)
            int b = (sn >> 5) & 1;
            int q0 = (sn << 1) & 63;
            int q1 = q0 | 1;
            int qo = b ? q1 : q0;                        // own candidate  (j=b)
            int qp = b ? q0 : q1;                        // partner's      (j=1-b)
            eo0[k] = ((b ^ (qo >> 5) ^ (qo >> 4) ^ (qo >> 3) ^ qo) & 1) != 0;
            eo1[k] = ((b ^ (qo >> 4) ^ (qo >> 3) ^ (qo >> 1) ^ qo) & 1) != 0;
            ep0[k] = ((b ^ (qp >> 5) ^ (qp >> 4) ^ (qp >> 3) ^ qp) & 1) != 0;
            ep1[k] = ((b ^ (qp >> 4) ^ (qp >> 3) ^ (qp >> 1) ^ qp) & 1) != 0;
        }
        // BBM[k]: mask of lanes with bit k set (= input bit b per lane)
        const unsigned long long BBM[6] = {
            0xAAAAAAAAAAAAAAAAull, 0xCCCCCCCCCCCCCCCCull, 0xF0F0F0F0F0F0F0F0ull,
            0xFF00FF00FF00FF00ull, 0xFFFF0000FFFF0000ull, 0xFFFFFFFF00000000ull };

        float m = 0.0f;
        float2 llA[6], llB[6];
        #pragma unroll
        for (int j = 0; j < 6; ++j) llA[j] = lq[j];
        #pragma unroll
        for (int j = 0; j < 6; ++j) llB[j] = lq[6 + j];

        for (int t6 = 0; t6 < 512; t6 += 2) {
            #pragma unroll
            for (int k = 0; k < 6; ++k) { const int t = t6 * 6 + k; STEP(llA[k], k, t); }
            #pragma unroll
            for (int j = 0; j < 6; ++j) llA[j] = lq[((t6 + 2) * 6 + j) & (DET - 1)];
            #pragma unroll
            for (int k = 0; k < 6; ++k) { const int t = (t6 + 1) * 6 + k; STEP(llB[k], k, t); }
            #pragma unroll
            for (int j = 0; j < 6; ++j) llB[j] = lq[((t6 + 3) * 6 + j) & (DET - 1)];
        }
    }
    __syncthreads();

    // ---- speculative traceback: wave w -> batch q=w&1, chunk c=w>>2? no: w>>1 ----
    {
        const int q = w & 1, c = w >> 1;          // chunk c: t in [1024+512c, 1024+512(c+1))
        const unsigned long long* dq = &decs[q][0];
        int st = L;                                // speculative state at top boundary
        unsigned int acc = 0;
        int tb0 = 1024 + 512 * c + 511;
        int rtop = (tb0 + 1) % 6;
        unsigned long long qa[8], qb[8];
        #pragma unroll
        for (int j = 0; j < 8; ++j) qa[j] = dq[tb0 - 1024 - j];
        for (int blk = 0; blk < 64; blk += 2) {
            const int tb1 = tb0 - 8;
            #pragma unroll
            for (int j = 0; j < 8; ++j) qb[j] = dq[tb1 - 1024 - j];
            TBSTEPS(qa, tb0, rtop);
            const int tb2 = tb0 - 16;
            if (blk + 2 < 64) {
                #pragma unroll
                for (int j = 0; j < 8; ++j) qa[j] = dq[tb2 - 1024 - j];
            }
            int rt1 = rtop - 2; if (rt1 < 0) rt1 += 6;
            TBSTEPS(qb, tb1, rt1);
            rtop = rt1 - 2; if (rtop < 0) rtop += 6;
            tb0 -= 16;
        }
        gmap[q][c][L] = (unsigned char)st;
    }
    __syncthreads();

    // ---- compose chunk maps (true state at t=3071 boundary is 0) ----
    if (tid < 2) {
        int s = 0;
        #pragma unroll
        for (int cc = 3; cc >= 0; --cc) { entry[tid][cc] = (unsigned char)s; s = gmap[tid][cc][s]; }
    }
    __syncthreads();

    // ---- gather the true path's bits ----
    if (tid < 64) {
        int q2 = tid >> 5, wi = tid & 31, cc = wi >> 4;
        bitw[q2][wi] = bitsl[q2][cc][entry[q2][cc]][wi & 15];
    }
    __syncthreads();

    // ---- coalesced output (2 batch rows = 2048 floats) ----
    float* orow = out + (size_t)bidx * 2048;
    #pragma unroll
    for (int rr = 0; rr < 4; ++rr) {
        int jj = rr * 512 + tid;
        int q2 = jj >> 10, ii = jj & 1023;
        orow[jj] = (float)((bitw[q2][ii >> 5] >> (ii & 31)) & 1u);
    }
}

extern "C" void kernel_launch(void* const* d_in, const int* in_sizes, int n_in,
                              void* d_out, int out_size, void* d_ws, size_t ws_size,
                              hipStream_t stream) {
    const float* x = (const float*)d_in[0];
    float* out = (float*)d_out;
    (void)in_sizes; (void)n_in; (void)d_ws; (void)ws_size; (void)out_size;
    hipLaunchKernelGGL(cva_kernel, dim3(256), dim3(512), 0, stream, x, out);
}

// Round 7
// 165.429 us; speedup vs baseline: 2.5803x; 1.7983x over previous
//
#include <hip/hip_runtime.h>

#define DET 1024
#define CLIPV 20.0f

// DPP lane permutation (quad_perm imm8, 0x140 row_mirror, 0x141 row_half_mirror)
template<int CTRL>
__device__ __forceinline__ float dppx(float v) {
    int i = __float_as_int(v);
    int r = __builtin_amdgcn_update_dpp(i, i, CTRL, 0xF, 0xF, false);
    return __int_as_float(r);
}
// Full exchange lane^16 via v_permlane16_swap_b32 (verified round 5).
__device__ __forceinline__ float xor16x(float v) {
    int a = __float_as_int(v);
    int b;
    asm("v_mov_b32 %1, %0\n\t"
        "s_nop 1\n\t"
        "v_permlane16_swap_b32 %0, %1\n\t"
        "s_nop 1"
        : "+v"(a), "=&v"(b));
    int mi = __float_as_int(v);
    return __int_as_float((a == mi) ? b : a);
}
// Full exchange lane^32 via v_permlane32_swap_b32 (verified round 5).
__device__ __forceinline__ float xor32x(float v) {
    int a = __float_as_int(v);
    int b;
    asm("v_mov_b32 %1, %0\n\t"
        "s_nop 1\n\t"
        "v_permlane32_swap_b32 %0, %1\n\t"
        "s_nop 1"
        : "+v"(a), "=&v"(b));
    int mi = __float_as_int(v);
    return __int_as_float((a == mi) ? b : a);
}

// Slim ACS step: ~14 VALU, no branches, no ballots, no exec manipulation.
#define STEPK(LL, K) do {                                                      \
    float mp;                                                                  \
    if ((K) == 0)      mp = dppx<0xB1>(m);                /* xor1  */          \
    else if ((K) == 1) mp = dppx<0x4E>(m);                /* xor2  */          \
    else if ((K) == 2) mp = dppx<0x141>(dppx<0x1B>(m));   /* xor4  */          \
    else if ((K) == 3) mp = dppx<0x140>(dppx<0x141>(m));  /* xor8  */          \
    else if ((K) == 4) mp = xor16x(m);                    /* xor16 */          \
    else               mp = xor32x(m);                    /* xor32 */          \
    float Bo = __builtin_fmaf(fo0[K], (LL).x, fo1[K] * (LL).y);                \
    float Bp = __builtin_fmaf(fp0[K], (LL).x, fp1[K] * (LL).y);                \
    float to = m + Bo;                                    /* candidate j=b  */ \
    float tp = mp + Bp;                                   /* candidate j=1-b*/ \
    float df = to - tp;                                                        \
    unsigned d = (sgn[K] * df > 0.0f) ? 1u : 0u;                               \
    acc = (acc << 1) | d;                                                      \
    float mn = fminf(to, tp);                                                  \
    m = fminf(fmaxf(mn, -CLIPV), CLIPV);                                       \
} while (0)

// 8 traceback steps from prefetched qword buffer (verified round 5).
#define TBSTEPS(QARR, TBTOP, RT) do {                                          \
    _Pragma("unroll")                                                          \
    for (int j = 0; j < 8; ++j) {                                              \
        const int t = (TBTOP) - j;                                             \
        int r = (RT) - (j % 6); if (r < 0) r += 6;                             \
        int Lx = ((st << r) | (st >> (6 - r))) & 63;                           \
        int bit = (int)((QARR[j] >> Lx) & 1ull);                               \
        if (c < 2) {                                                           \
            unsigned int ob = (~(unsigned)st) & 1u;                            \
            int i = t - 1024;                                                  \
            acc |= ob << (i & 31);                                             \
            if ((i & 31) == 0) { bitsl[q][c][L][(i >> 5) & 15] = acc; acc = 0; }\
        }                                                                      \
        st = ((st << 1) | bit) & 63;                                           \
    }                                                                          \
} while (0)

// 256 blocks x 512 threads; block owns batches 2*bidx, 2*bidx+1.
// Waves 0,1: forward ACS. All 8 waves: transpose + speculative traceback.
__global__ __launch_bounds__(512) void cva_kernel(const float* __restrict__ x,
                                                  float* __restrict__ out) {
    const int bidx = blockIdx.x;
    const int tid  = threadIdx.x;
    const int L    = tid & 63;
    const int w    = tid >> 6;

    __shared__ float2 lx[2][DET];                 // 16 KB
    __shared__ unsigned int decw[2][96 * 64];     // 48 KB per-lane decision words
    __shared__ unsigned long long masks[2][2048]; // 32 KB t-indexed decision masks
    __shared__ unsigned int bitsl[2][2][64][16];  // 16 KB speculative bit strings
    __shared__ unsigned char gmap[2][4][64];
    __shared__ unsigned char entry[2][4];
    __shared__ unsigned int bitw[2][32];

    // ---- stage both batches' LLRs (coalesced) ----
    const float2* __restrict__ xr2 =
        reinterpret_cast<const float2*>(x + (size_t)bidx * 4096);
    float2* lxf = &lx[0][0];
    for (int i = tid; i < 2048; i += 512) lxf[i] = xr2[i];
    __syncthreads();

    // ---- forward ACS: waves 0,1 (one batch each) ----
    if (w < 2) {
        const float2* lq = &lx[w][0];
        unsigned int* dqw = &decw[w][0];

        // per-phase per-lane edge constants as floats in {0,1}; sgn = +-1
        float fo0[6], fo1[6], fp0[6], fp1[6], sgn[6];
        #pragma unroll
        for (int k = 0; k < 6; ++k) {
            int r = (k + 1) % 6;
            int sn = ((L >> r) | (L << (6 - r))) & 63;   // rotr6(L, r)
            int b = (sn >> 5) & 1;
            int q0 = (sn << 1) & 63;
            int q1 = q0 | 1;
            int qo = b ? q1 : q0;                        // own candidate  (j=b)
            int qp = b ? q0 : q1;                        // partner's      (j=1-b)
            fo0[k] = (float)((b ^ (qo >> 5) ^ (qo >> 4) ^ (qo >> 3) ^ qo) & 1);
            fo1[k] = (float)((b ^ (qo >> 4) ^ (qo >> 3) ^ (qo >> 1) ^ qo) & 1);
            fp0[k] = (float)((b ^ (qp >> 5) ^ (qp >> 4) ^ (qp >> 3) ^ qp) & 1);
            fp1[k] = (float)((b ^ (qp >> 4) ^ (qp >> 3) ^ (qp >> 1) ^ qp) & 1);
            sgn[k] = b ? -1.0f : 1.0f;
        }

        float m = 0.0f;
        unsigned acc = 0;
        float2 llA[6], llB[6];
        #pragma unroll
        for (int j = 0; j < 6; ++j) llA[j] = lq[j];
        #pragma unroll
        for (int j = 0; j < 6; ++j) llB[j] = lq[6 + j];
        int nidx = 12;                         // next group's first element index
        int wrow = 0;                          // decw row offset = 3*mi*64

        for (int mi = 0; mi < 32; ++mi) {      // 32 macro-iterations x 96 steps
            #pragma unroll
            for (int g = 0; g < 16; ++g) {
                if ((g & 1) == 0) {
                    STEPK(llA[0], 0); STEPK(llA[1], 1);
                    if (g == 5)  dqw[wrow + L] = acc;            // t = 96mi+31
                    STEPK(llA[2], 2); STEPK(llA[3], 3);
                    if (g == 10) dqw[wrow + 64 + L] = acc;       // t = 96mi+63
                    STEPK(llA[4], 4); STEPK(llA[5], 5);
                    if (g == 15) dqw[wrow + 128 + L] = acc;      // t = 96mi+95
                    #pragma unroll
                    for (int j = 0; j < 6; ++j) llA[j] = lq[(nidx + j) & (DET - 1)];
                } else {
                    STEPK(llB[0], 0); STEPK(llB[1], 1);
                    if (g == 5)  dqw[wrow + L] = acc;
                    STEPK(llB[2], 2); STEPK(llB[3], 3);
                    if (g == 10) dqw[wrow + 64 + L] = acc;
                    STEPK(llB[4], 4); STEPK(llB[5], 5);
                    if (g == 15) dqw[wrow + 128 + L] = acc;
                    #pragma unroll
                    for (int j = 0; j < 6; ++j) llB[j] = lq[(nidx + j) & (DET - 1)];
                }
                nidx += 6;
            }
            wrow += 3 * 64;
        }
    }
    __syncthreads();

    // ---- bit-transpose decw -> t-indexed u64 masks (t >= 1024 only) ----
    // decw word W of lane j, window tw: bit p = decision of lane j at
    // t = tw*32 + 31 - p. Assemble masks via ballot + select (no writelane).
    for (int n = 0; n < 16; ++n) {
        int jw = w + 8 * n;                    // 128 jobs: 2 batches x 64 windows
        int q = jw & 1;
        int tw = 32 + (jw >> 1);
        unsigned W = decw[q][tw * 64 + L];
        unsigned mlo = 0, mhi = 0;
        #pragma unroll
        for (int i = 0; i < 32; ++i) {
            unsigned long long bal = __ballot(((W >> (31 - i)) & 1u) != 0);
            bool sel = (L == i);                       // lane i keeps t = tw*32+i
            mlo = sel ? (unsigned)bal : mlo;           // branchless cndmask
            mhi = sel ? (unsigned)(bal >> 32) : mhi;
        }
        if (L < 32) {
            masks[q][(tw - 32) * 32 + L] =
                ((unsigned long long)mhi << 32) | mlo; // index = t - 1024
        }
    }
    __syncthreads();

    // ---- speculative traceback (verified round-5 structure) ----
    {
        const int q = w & 1, c = w >> 1;       // chunk c: t in [1024+512c, 1024+512(c+1))
        const unsigned long long* dq = &masks[q][0];
        int st = L;                            // speculative state at top boundary
        unsigned int acc = 0;
        int tb0 = 1024 + 512 * c + 511;
        int rtop = (tb0 + 1) % 6;
        unsigned long long qa[8], qb[8];
        #pragma unroll
        for (int j = 0; j < 8; ++j) qa[j] = dq[tb0 - 1024 - j];
        for (int blk = 0; blk < 64; blk += 2) {
            const int tb1 = tb0 - 8;
            #pragma unroll
            for (int j = 0; j < 8; ++j) qb[j] = dq[tb1 - 1024 - j];
            TBSTEPS(qa, tb0, rtop);
            const int tb2 = tb0 - 16;
            if (blk + 2 < 64) {
                #pragma unroll
                for (int j = 0; j < 8; ++j) qa[j] = dq[tb2 - 1024 - j];
            }
            int rt1 = rtop - 2; if (rt1 < 0) rt1 += 6;
            TBSTEPS(qb, tb1, rt1);
            rtop = rt1 - 2; if (rtop < 0) rtop += 6;
            tb0 -= 16;
        }
        gmap[q][c][L] = (unsigned char)st;
    }
    __syncthreads();

    // ---- compose chunk maps (true state at t=3071 boundary is 0) ----
    if (tid < 2) {
        int s = 0;
        #pragma unroll
        for (int cc = 3; cc >= 0; --cc) { entry[tid][cc] = (unsigned char)s; s = gmap[tid][cc][s]; }
    }
    __syncthreads();

    // ---- gather the true path's bits ----
    if (tid < 64) {
        int q2 = tid >> 5, wi = tid & 31, cc = wi >> 4;
        bitw[q2][wi] = bitsl[q2][cc][entry[q2][cc]][wi & 15];
    }
    __syncthreads();

    // ---- coalesced output (2 batch rows = 2048 floats) ----
    float* orow = out + (size_t)bidx * 2048;
    #pragma unroll
    for (int rr = 0; rr < 4; ++rr) {
        int jj = rr * 512 + tid;
        int q2 = jj >> 10, ii = jj & 1023;
        orow[jj] = (float)((bitw[q2][ii >> 5] >> (ii & 31)) & 1u);
    }
}

extern "C" void kernel_launch(void* const* d_in, const int* in_sizes, int n_in,
                              void* d_out, int out_size, void* d_ws, size_t ws_size,
                              hipStream_t stream) {
    const float* x = (const float*)d_in[0];
    float* out = (float*)d_out;
    (void)in_sizes; (void)n_in; (void)d_ws; (void)ws_size; (void)out_size;
    hipLaunchKernelGGL(cva_kernel, dim3(256), dim3(512), 0, stream, x, out);
}

// Round 8
// 144.213 us; speedup vs baseline: 2.9600x; 1.1471x over previous
//
#include <hip/hip_runtime.h>

#define DET 1024
#define CLIPV 20.0f

// DPP lane permutation (quad_perm imm8, 0x140 row_mirror, 0x141 row_half_mirror)
template<int CTRL>
__device__ __forceinline__ float dppx(float v) {
    int i = __float_as_int(v);
    int r = __builtin_amdgcn_update_dpp(i, i, CTRL, 0xF, 0xF, false);
    return __int_as_float(r);
}

// Slim ACS step. Exchange for k4/k5 uses permlane swap with a PRE-PROBED
// orientation mask (useA16/useA32): in-loop cost = copy + swap + cndmask.
// m is dead after `to = m + Bo`, so the swap may clobber it.
#define STEPK(LL, K) do {                                                      \
    float Bo = __builtin_fmaf(fo0[K], (LL).x, fo1[K] * (LL).y);                \
    float Bp = __builtin_fmaf(fp0[K], (LL).x, fp1[K] * (LL).y);                \
    float to = m + Bo;                                    /* candidate j=b  */ \
    float mp;                                                                  \
    if ((K) == 0)      mp = dppx<0xB1>(m);                /* xor1  */          \
    else if ((K) == 1) mp = dppx<0x4E>(m);                /* xor2  */          \
    else if ((K) == 2) mp = dppx<0x141>(dppx<0x1B>(m));   /* xor4  */          \
    else if ((K) == 3) mp = dppx<0x140>(dppx<0x141>(m));  /* xor8  */          \
    else if ((K) == 4) {                                                       \
        int a1 = __float_as_int(m), a2 = a1;                                   \
        asm("s_nop 1\n\tv_permlane16_swap_b32 %0, %1\n\ts_nop 1"               \
            : "+v"(a1), "+v"(a2));                                             \
        mp = __int_as_float(useA16 ? a1 : a2);                                 \
    } else {                                                                   \
        int a1 = __float_as_int(m), a2 = a1;                                   \
        asm("s_nop 1\n\tv_permlane32_swap_b32 %0, %1\n\ts_nop 1"               \
            : "+v"(a1), "+v"(a2));                                             \
        mp = __int_as_float(useA32 ? a1 : a2);                                 \
    }                                                                          \
    float tp = mp + Bp;                                   /* candidate j=1-b*/ \
    float slo = sgn[K] * to, slp = sgn[K] * tp;                                \
    acc = acc + acc + (slp < slo ? 1u : 0u);              /* (acc<<1)|d */     \
    m = __builtin_amdgcn_fmed3f(fminf(to, tp), -CLIPV, CLIPV);                 \
} while (0)

// 8 traceback steps from prefetched qword buffer (verified round 5).
#define TBSTEPS(QARR, TBTOP, RT) do {                                          \
    _Pragma("unroll")                                                          \
    for (int j = 0; j < 8; ++j) {                                              \
        const int t = (TBTOP) - j;                                             \
        int r = (RT) - (j % 6); if (r < 0) r += 6;                             \
        int Lx = ((st << r) | (st >> (6 - r))) & 63;                           \
        int bit = (int)((QARR[j] >> Lx) & 1ull);                               \
        if (c < 2) {                                                           \
            unsigned int ob = (~(unsigned)st) & 1u;                            \
            int i = t - 1024;                                                  \
            acc |= ob << (i & 31);                                             \
            if ((i & 31) == 0) { bitsl[q][c][L][(i >> 5) & 15] = acc; acc = 0; }\
        }                                                                      \
        st = ((st << 1) | bit) & 63;                                           \
    }                                                                          \
} while (0)

// 256 blocks x 512 threads; block owns batches 2*bidx, 2*bidx+1.
// Waves 0,1: forward ACS. All 8 waves: transpose + speculative traceback.
__global__ __launch_bounds__(512) void cva_kernel(const float* __restrict__ x,
                                                  float* __restrict__ out) {
    const int bidx = blockIdx.x;
    const int tid  = threadIdx.x;
    const int L    = tid & 63;
    const int w    = tid >> 6;

    __shared__ float2 lx[2][DET + 8];             // padded: head replicated at tail
    __shared__ unsigned int decw[2][96 * 64];     // 48 KB per-lane decision words
    __shared__ unsigned long long masks[2][2048]; // 32 KB t-indexed decision masks
    __shared__ unsigned int bitsl[2][2][64][16];  // 16 KB speculative bit strings
    __shared__ unsigned char gmap[2][4][64];
    __shared__ unsigned char entry[2][4];
    __shared__ unsigned int bitw[2][32];

    // ---- stage both batches' LLRs (coalesced) + replicated 8-entry tail ----
    const float2* __restrict__ xr2 =
        reinterpret_cast<const float2*>(x + (size_t)bidx * 4096);
    for (int i = tid; i < 2048; i += 512) lx[i >> 10][i & 1023] = xr2[i];
    if (tid < 16) lx[tid >> 3][DET + (tid & 7)] = xr2[(tid >> 3) * DET + (tid & 7)];
    __syncthreads();

    // ---- forward ACS: waves 0,1 (one batch each) ----
    if (w < 2) {
        const float2* lq = &lx[w][0];
        unsigned int* dqw = &decw[w][0];

        // probe permlane swap orientation ONCE (loop-invariant select masks)
        bool useA16, useA32;
        {
            int p1 = L, p2 = L;
            asm("s_nop 1\n\tv_permlane16_swap_b32 %0, %1\n\ts_nop 1"
                : "+v"(p1), "+v"(p2));
            useA16 = (p1 == (L ^ 16));
            int q1 = L, q2 = L;
            asm("s_nop 1\n\tv_permlane32_swap_b32 %0, %1\n\ts_nop 1"
                : "+v"(q1), "+v"(q2));
            useA32 = (q1 == (L ^ 32));
        }

        // per-phase per-lane edge constants as floats in {0,1}; sgn = +-1
        float fo0[6], fo1[6], fp0[6], fp1[6], sgn[6];
        #pragma unroll
        for (int k = 0; k < 6; ++k) {
            int r = (k + 1) % 6;
            int sn = ((L >> r) | (L << (6 - r))) & 63;   // rotr6(L, r)
            int b = (sn >> 5) & 1;
            int q0 = (sn << 1) & 63;
            int q1 = q0 | 1;
            int qo = b ? q1 : q0;                        // own candidate  (j=b)
            int qp = b ? q0 : q1;                        // partner's      (j=1-b)
            fo0[k] = (float)((b ^ (qo >> 5) ^ (qo >> 4) ^ (qo >> 3) ^ qo) & 1);
            fo1[k] = (float)((b ^ (qo >> 4) ^ (qo >> 3) ^ (qo >> 1) ^ qo) & 1);
            fp0[k] = (float)((b ^ (qp >> 5) ^ (qp >> 4) ^ (qp >> 3) ^ qp) & 1);
            fp1[k] = (float)((b ^ (qp >> 4) ^ (qp >> 3) ^ (qp >> 1) ^ qp) & 1);
            sgn[k] = b ? -1.0f : 1.0f;
        }

        float m = 0.0f;
        unsigned acc = 0;
        float2 llA[6], llB[6];
        #pragma unroll
        for (int j = 0; j < 6; ++j) llA[j] = lq[j];
        #pragma unroll
        for (int j = 0; j < 6; ++j) llB[j] = lq[6 + j];
        int nidx = 12;                         // next group's first element index
        int wrow = 0;                          // decw row offset = 3*mi*64

        for (int mi = 0; mi < 32; ++mi) {      // 32 macro-iterations x 96 steps
            #pragma unroll
            for (int g = 0; g < 16; ++g) {
                if ((g & 1) == 0) {
                    STEPK(llA[0], 0); STEPK(llA[1], 1);
                    if (g == 5)  dqw[wrow + L] = acc;            // t = 96mi+31
                    STEPK(llA[2], 2); STEPK(llA[3], 3);
                    if (g == 10) dqw[wrow + 64 + L] = acc;       // t = 96mi+63
                    STEPK(llA[4], 4); STEPK(llA[5], 5);
                    if (g == 15) dqw[wrow + 128 + L] = acc;      // t = 96mi+95
                    const float2* pp = lq + (nidx & (DET - 1));  // padded tail
                    #pragma unroll
                    for (int j = 0; j < 6; ++j) llA[j] = pp[j];  // imm offsets
                } else {
                    STEPK(llB[0], 0); STEPK(llB[1], 1);
                    if (g == 5)  dqw[wrow + L] = acc;
                    STEPK(llB[2], 2); STEPK(llB[3], 3);
                    if (g == 10) dqw[wrow + 64 + L] = acc;
                    STEPK(llB[4], 4); STEPK(llB[5], 5);
                    if (g == 15) dqw[wrow + 128 + L] = acc;
                    const float2* pp = lq + (nidx & (DET - 1));
                    #pragma unroll
                    for (int j = 0; j < 6; ++j) llB[j] = pp[j];
                }
                nidx += 6;
            }
            wrow += 3 * 64;
        }
    }
    __syncthreads();

    // ---- bit-transpose decw -> t-indexed u64 masks (t >= 1024 only) ----
    for (int n = 0; n < 16; ++n) {
        int jw = w + 8 * n;                    // 128 jobs: 2 batches x 64 windows
        int q = jw & 1;
        int tw = 32 + (jw >> 1);
        unsigned W = decw[q][tw * 64 + L];
        unsigned mlo = 0, mhi = 0;
        #pragma unroll
        for (int i = 0; i < 32; ++i) {
            unsigned long long bal = __ballot(((W >> (31 - i)) & 1u) != 0);
            bool sel = (L == i);                       // lane i keeps t = tw*32+i
            mlo = sel ? (unsigned)bal : mlo;
            mhi = sel ? (unsigned)(bal >> 32) : mhi;
        }
        if (L < 32) {
            masks[q][(tw - 32) * 32 + L] =
                ((unsigned long long)mhi << 32) | mlo; // index = t - 1024
        }
    }
    __syncthreads();

    // ---- speculative traceback (verified round-5 structure) ----
    {
        const int q = w & 1, c = w >> 1;       // chunk c: t in [1024+512c, 1024+512(c+1))
        const unsigned long long* dq = &masks[q][0];
        int st = L;                            // speculative state at top boundary
        unsigned int acc = 0;
        int tb0 = 1024 + 512 * c + 511;
        int rtop = (tb0 + 1) % 6;
        unsigned long long qa[8], qb[8];
        #pragma unroll
        for (int j = 0; j < 8; ++j) qa[j] = dq[tb0 - 1024 - j];
        for (int blk = 0; blk < 64; blk += 2) {
            const int tb1 = tb0 - 8;
            #pragma unroll
            for (int j = 0; j < 8; ++j) qb[j] = dq[tb1 - 1024 - j];
            TBSTEPS(qa, tb0, rtop);
            const int tb2 = tb0 - 16;
            if (blk + 2 < 64) {
                #pragma unroll
                for (int j = 0; j < 8; ++j) qa[j] = dq[tb2 - 1024 - j];
            }
            int rt1 = rtop - 2; if (rt1 < 0) rt1 += 6;
            TBSTEPS(qb, tb1, rt1);
            rtop = rt1 - 2; if (rtop < 0) rtop += 6;
            tb0 -= 16;
        }
        gmap[q][c][L] = (unsigned char)st;
    }
    __syncthreads();

    // ---- compose chunk maps (true state at t=3071 boundary is 0) ----
    if (tid < 2) {
        int s = 0;
        #pragma unroll
        for (int cc = 3; cc >= 0; --cc) { entry[tid][cc] = (unsigned char)s; s = gmap[tid][cc][s]; }
    }
    __syncthreads();

    // ---- gather the true path's bits ----
    if (tid < 64) {
        int q2 = tid >> 5, wi = tid & 31, cc = wi >> 4;
        bitw[q2][wi] = bitsl[q2][cc][entry[q2][cc]][wi & 15];
    }
    __syncthreads();

    // ---- coalesced output (2 batch rows = 2048 floats) ----
    float* orow = out + (size_t)bidx * 2048;
    #pragma unroll
    for (int rr = 0; rr < 4; ++rr) {
        int jj = rr * 512 + tid;
        int q2 = jj >> 10, ii = jj & 1023;
        orow[jj] = (float)((bitw[q2][ii >> 5] >> (ii & 31)) & 1u);
    }
}

extern "C" void kernel_launch(void* const* d_in, const int* in_sizes, int n_in,
                              void* d_out, int out_size, void* d_ws, size_t ws_size,
                              hipStream_t stream) {
    const float* x = (const float*)d_in[0];
    float* out = (float*)d_out;
    (void)in_sizes; (void)n_in; (void)d_ws; (void)ws_size; (void)out_size;
    hipLaunchKernelGGL(cva_kernel, dim3(256), dim3(512), 0, stream, x, out);
}